// Round 6
// baseline (495.512 us; speedup 1.0000x reference)
//
#include <hip/hip_runtime.h>
#include <hip/hip_bf16.h>
#include <stdint.h>

#define NN 50000
#define NE 600000
#define IN_DIM 512
#define HID 128
#define ODIM 64
#define EPSV 0.1f
#define NBLK ((NN + 255) / 256)  // 196 scan blocks

typedef __attribute__((ext_vector_type(8))) short short8;
typedef __attribute__((ext_vector_type(4))) float f32x4;

__device__ __forceinline__ ushort f2bf(float f) {
    union { float f; uint32_t i; } v; v.f = f;
    uint32_t lsb = (v.i >> 16) & 1u;
    uint32_t r = v.i + 0x7fffu + lsb;
    return (ushort)(r >> 16);
}

// fast tanh: (e^2z - 1) / (e^2z + 1), clamped
__device__ __forceinline__ float fast_tanh(float z) {
    z = fminf(fmaxf(z, -15.f), 15.f);
    float t = __expf(2.f * z);
    return __fdividef(t - 1.f, t + 1.f);
}

// ---- degree count ----
__global__ __launch_bounds__(256) void deg_kernel(const int* __restrict__ dst, int* __restrict__ deg) {
    int e = blockIdx.x * 256 + threadIdx.x;
    if (e < NE) atomicAdd(&deg[dst[e]], 1);
}

// ---- scan phase A ----
__global__ __launch_bounds__(256) void scanA_kernel(const int* __restrict__ deg,
                                                    int* __restrict__ localScan,
                                                    int* __restrict__ blockSums,
                                                    float* __restrict__ dinv) {
    __shared__ int tmp[256];
    int t = threadIdx.x;
    int i = blockIdx.x * 256 + t;
    int v = (i < NN) ? deg[i] : 0;
    tmp[t] = v;
    __syncthreads();
    for (int off = 1; off < 256; off <<= 1) {
        int add = (t >= off) ? tmp[t - off] : 0;
        __syncthreads();
        tmp[t] += add;
        __syncthreads();
    }
    if (i < NN) {
        localScan[i] = tmp[t] - v;
        dinv[i] = (v > 0) ? (1.0f / sqrtf((float)v)) : 0.0f;
    }
    if (t == 255) blockSums[blockIdx.x] = tmp[255];
}

// ---- scan phase B ----
__global__ __launch_bounds__(256) void scanB_kernel(const int* __restrict__ blockSums,
                                                    int* __restrict__ blockOff) {
    __shared__ int tmp[256];
    int t = threadIdx.x;
    int v = (t < NBLK) ? blockSums[t] : 0;
    tmp[t] = v;
    __syncthreads();
    for (int off = 1; off < 256; off <<= 1) {
        int add = (t >= off) ? tmp[t - off] : 0;
        __syncthreads();
        tmp[t] += add;
        __syncthreads();
    }
    blockOff[t] = tmp[t] - v;
}

// ---- scan phase C ----
__global__ __launch_bounds__(256) void scanC_kernel(const int* __restrict__ localScan,
                                                    const int* __restrict__ blockOff,
                                                    int* __restrict__ rowptr,
                                                    int* __restrict__ cursor) {
    int i = blockIdx.x * 256 + threadIdx.x;
    if (i < NN) {
        int v = localScan[i] + blockOff[blockIdx.x];
        rowptr[i] = v;
        cursor[i] = v;
    }
    if (i == 0) rowptr[NN] = NE;
}

// ---- fill CSR ----
__global__ __launch_bounds__(256) void fill_kernel(const int* __restrict__ src, const int* __restrict__ dst,
                                                   int* __restrict__ cursor, int* __restrict__ csr_src) {
    int e = blockIdx.x * 256 + threadIdx.x;
    if (e < NE) {
        int d = dst[e];
        int slot = atomicAdd(&cursor[d], 1);
        csr_src[slot] = src[e];
    }
}

// ---- convert W1 fp32 -> bf16 ----
__global__ __launch_bounds__(256) void cvtw_kernel(const float* __restrict__ w, ushort* __restrict__ wbf) {
    int i = blockIdx.x * 256 + threadIdx.x;
    if (i < HID * IN_DIM) wbf[i] = f2bf(w[i]);
}

// ---- h0 = relu(x @ W1^T + b1): pipelined 64-row tile, LDS bf16 A-staging ----
// Block: 64 rows x 128 cols, K in 8 steps of 64. Wave wv owns rows [wv*16, wv*16+16).
// LDS A-tile row stride 72 bf16 (pad 8) -> conflict-free ds_read_b128 fragments.
// Register prefetch: next K-step's global loads issued before current compute.
__global__ __launch_bounds__(256) void gemm1_kernel(const float* __restrict__ x,
                                                    const ushort* __restrict__ wbf,
                                                    const float* __restrict__ b,
                                                    float* __restrict__ h) {
    __shared__ ushort a_sm[64 * 72]; // 9 KB
    int t = threadIdx.x;
    int wv = __builtin_amdgcn_readfirstlane(t >> 6);
    int lane = t & 63;
    int m0 = blockIdx.x * 64;

    // staging map: thread t covers rows tr+16i, cols [tc, tc+4)
    int tr = t >> 4;          // 0..15
    int tc = (t & 15) * 4;    // 0..60

    // fragment map
    int rsel = lane & 15;
    int koff = (lane >> 4) * 8;
    int rloc = wv * 16 + rsel;

    f32x4 acc[8];
#pragma unroll
    for (int tt = 0; tt < 8; ++tt) acc[tt] = (f32x4){0.f, 0.f, 0.f, 0.f};

    // prologue: load K-step 0
    float4 p0, p1, p2, p3;
    {
        int r0 = m0 + tr;        if (r0 >= NN) r0 = NN - 1;
        int r1 = m0 + tr + 16;   if (r1 >= NN) r1 = NN - 1;
        int r2 = m0 + tr + 32;   if (r2 >= NN) r2 = NN - 1;
        int r3 = m0 + tr + 48;   if (r3 >= NN) r3 = NN - 1;
        p0 = *(const float4*)(x + (size_t)r0 * IN_DIM + tc);
        p1 = *(const float4*)(x + (size_t)r1 * IN_DIM + tc);
        p2 = *(const float4*)(x + (size_t)r2 * IN_DIM + tc);
        p3 = *(const float4*)(x + (size_t)r3 * IN_DIM + tc);
    }

    for (int s = 0; s < 8; ++s) {
        // write prefetched regs to LDS as bf16
        {
            uint2 u;
            u.x = (uint32_t)f2bf(p0.x) | ((uint32_t)f2bf(p0.y) << 16);
            u.y = (uint32_t)f2bf(p0.z) | ((uint32_t)f2bf(p0.w) << 16);
            *(uint2*)(&a_sm[(tr) * 72 + tc]) = u;
            u.x = (uint32_t)f2bf(p1.x) | ((uint32_t)f2bf(p1.y) << 16);
            u.y = (uint32_t)f2bf(p1.z) | ((uint32_t)f2bf(p1.w) << 16);
            *(uint2*)(&a_sm[(tr + 16) * 72 + tc]) = u;
            u.x = (uint32_t)f2bf(p2.x) | ((uint32_t)f2bf(p2.y) << 16);
            u.y = (uint32_t)f2bf(p2.z) | ((uint32_t)f2bf(p2.w) << 16);
            *(uint2*)(&a_sm[(tr + 32) * 72 + tc]) = u;
            u.x = (uint32_t)f2bf(p3.x) | ((uint32_t)f2bf(p3.y) << 16);
            u.y = (uint32_t)f2bf(p3.z) | ((uint32_t)f2bf(p3.w) << 16);
            *(uint2*)(&a_sm[(tr + 48) * 72 + tc]) = u;
        }
        __syncthreads();
        // fire next K-step's loads (stay in flight through compute + barrier)
        if (s + 1 < 8) {
            int k0n = (s + 1) * 64;
            int r0 = m0 + tr;        if (r0 >= NN) r0 = NN - 1;
            int r1 = m0 + tr + 16;   if (r1 >= NN) r1 = NN - 1;
            int r2 = m0 + tr + 32;   if (r2 >= NN) r2 = NN - 1;
            int r3 = m0 + tr + 48;   if (r3 >= NN) r3 = NN - 1;
            p0 = *(const float4*)(x + (size_t)r0 * IN_DIM + k0n + tc);
            p1 = *(const float4*)(x + (size_t)r1 * IN_DIM + k0n + tc);
            p2 = *(const float4*)(x + (size_t)r2 * IN_DIM + k0n + tc);
            p3 = *(const float4*)(x + (size_t)r3 * IN_DIM + k0n + tc);
        }
        // compute current step from LDS
        int k0 = s * 64;
#pragma unroll
        for (int kk = 0; kk < 64; kk += 32) {
            short8 a = *(const short8*)(&a_sm[rloc * 72 + kk + koff]);
#pragma unroll
            for (int tt = 0; tt < 8; ++tt) {
                short8 bf = *(const short8*)(wbf + (size_t)(tt * 16 + rsel) * IN_DIM + k0 + kk + koff);
                acc[tt] = __builtin_amdgcn_mfma_f32_16x16x32_bf16(a, bf, acc[tt], 0, 0, 0);
            }
        }
        __syncthreads();
    }

    // epilogue: bias + relu, straight from accumulators
    int rbase = (lane >> 4) * 4;
    int col0 = lane & 15;
#pragma unroll
    for (int tt = 0; tt < 8; ++tt) {
        int n = tt * 16 + col0;
        float bias = b[n];
#pragma unroll
        for (int r = 0; r < 4; ++r) {
            int row = m0 + wv * 16 + rbase + r;
            if (row < NN) {
                float v = acc[tt][r] + bias;
                v = v > 0.f ? v : 0.f;
                h[(size_t)row * HID + n] = v;
            }
        }
    }
}

// ---- per-node attention scalars for layer 0 ----
__global__ __launch_bounds__(256) void att0_kernel(const float* __restrict__ h,
                                                   const float* __restrict__ attl,
                                                   const float* __restrict__ attr,
                                                   const float* __restrict__ dinv,
                                                   float2* __restrict__ AD,
                                                   float* __restrict__ AR) {
    int wv = __builtin_amdgcn_readfirstlane(threadIdx.x >> 6);
    int lane = threadIdx.x & 63;
    int d = blockIdx.x * 4 + wv;
    if (d >= NN) return;
    float al0 = attl[2 * lane], al1 = attl[2 * lane + 1];
    float ar0 = attr[2 * lane], ar1 = attr[2 * lane + 1];
    float2 hd = ((const float2*)h)[(size_t)d * 64 + lane];
    float p = hd.x * al0 + hd.y * al1;
    float q = hd.x * ar0 + hd.y * ar1;
#pragma unroll
    for (int off = 32; off; off >>= 1) { p += __shfl_xor(p, off); q += __shfl_xor(q, off); }
    if (lane == 0) {
        float2 v; v.x = p; v.y = dinv[d];
        AD[d] = v;
        AR[d] = q;
    }
}

// ---- FAConv aggregation: wave per dst node ----
__global__ __launch_bounds__(256) void agg_kernel(const float* __restrict__ h,
                                                  const float* __restrict__ raw,
                                                  float* __restrict__ hn,
                                                  const int* __restrict__ rowptr,
                                                  const int* __restrict__ csr_src,
                                                  const float* __restrict__ dinv,
                                                  const float2* __restrict__ AD,
                                                  const float* __restrict__ AR,
                                                  const float* __restrict__ attl_next,
                                                  const float* __restrict__ attr_next,
                                                  float2* __restrict__ ADout,
                                                  float* __restrict__ ARout) {
    int wv = __builtin_amdgcn_readfirstlane(threadIdx.x >> 6);
    int lane = threadIdx.x & 63;
    int d = blockIdx.x * 4 + wv;
    if (d >= NN) return;
    const float2* h2 = (const float2*)h;
    float ar_d = AR[d];
    float dinv_d = dinv[d];
    float2 rawd = ((const float2*)raw)[(size_t)d * 64 + lane];
    float accx = EPSV * rawd.x, accy = EPSV * rawd.y;
    int e = rowptr[d], e1 = rowptr[d + 1];
    for (; e + 4 <= e1; e += 4) {
        int s0 = __builtin_amdgcn_readfirstlane(csr_src[e]);
        int s1 = __builtin_amdgcn_readfirstlane(csr_src[e + 1]);
        int s2 = __builtin_amdgcn_readfirstlane(csr_src[e + 2]);
        int s3 = __builtin_amdgcn_readfirstlane(csr_src[e + 3]);
        float2 ad0 = AD[s0], ad1 = AD[s1], ad2 = AD[s2], ad3 = AD[s3];
        float2 v0 = h2[(size_t)s0 * 64 + lane];
        float2 v1 = h2[(size_t)s1 * 64 + lane];
        float2 v2 = h2[(size_t)s2 * 64 + lane];
        float2 v3 = h2[(size_t)s3 * 64 + lane];
        float w0 = fast_tanh(ad0.x + ar_d) * ad0.y * dinv_d;
        float w1 = fast_tanh(ad1.x + ar_d) * ad1.y * dinv_d;
        float w2 = fast_tanh(ad2.x + ar_d) * ad2.y * dinv_d;
        float w3 = fast_tanh(ad3.x + ar_d) * ad3.y * dinv_d;
        accx += w0 * v0.x + w1 * v1.x + w2 * v2.x + w3 * v3.x;
        accy += w0 * v0.y + w1 * v1.y + w2 * v2.y + w3 * v3.y;
    }
    for (; e < e1; ++e) {
        int s = __builtin_amdgcn_readfirstlane(csr_src[e]);
        float2 ad = AD[s];
        float2 v = h2[(size_t)s * 64 + lane];
        float w = fast_tanh(ad.x + ar_d) * ad.y * dinv_d;
        accx += w * v.x;
        accy += w * v.y;
    }
    float2 o; o.x = accx; o.y = accy;
    ((float2*)hn)[(size_t)d * 64 + lane] = o;
    if (attl_next) {
        float al0 = attl_next[2 * lane], al1 = attl_next[2 * lane + 1];
        float ar0 = attr_next[2 * lane], ar1 = attr_next[2 * lane + 1];
        float p = accx * al0 + accy * al1;
        float q = accx * ar0 + accy * ar1;
#pragma unroll
        for (int off = 32; off; off >>= 1) { p += __shfl_xor(p, off); q += __shfl_xor(q, off); }
        if (lane == 0) {
            float2 v; v.x = p; v.y = dinv_d;
            ADout[d] = v;
            ARout[d] = q;
        }
    }
}

// ---- head: emb = h @ W2^T + b2; out0 = log_softmax(emb); out1 = emb ----
__global__ __launch_bounds__(256) void head_kernel(const float* __restrict__ h,
                                                   const float* __restrict__ w2,
                                                   const float* __restrict__ b2,
                                                   float* __restrict__ out) {
    __shared__ float w2t[HID * 65];
    int t = threadIdx.x;
    for (int i = t; i < HID * ODIM; i += 256) {
        int j = i >> 7, k = i & 127;
        w2t[k * 65 + j] = w2[i];
    }
    __syncthreads();
    int lane = t & 63;
    int wv = __builtin_amdgcn_readfirstlane(t >> 6);
    int d = blockIdx.x * 4 + wv;
    if (d >= NN) return;
    const float* hr = h + (size_t)d * HID;
    float ea = b2[lane], eb = 0.f;
#pragma unroll 8
    for (int k = 0; k < HID; k += 2) {
        ea += hr[k] * w2t[k * 65 + lane];
        eb += hr[k + 1] * w2t[(k + 1) * 65 + lane];
    }
    float e = ea + eb;
    float m = e;
#pragma unroll
    for (int off = 32; off; off >>= 1) m = fmaxf(m, __shfl_xor(m, off));
    float ex = __expf(e - m);
    float s = ex;
#pragma unroll
    for (int off = 32; off; off >>= 1) s += __shfl_xor(s, off);
    float lsm = e - m - __logf(s);
    out[(size_t)d * ODIM + lane] = lsm;
    out[(size_t)NN * ODIM + (size_t)d * ODIM + lane] = e;
}

extern "C" void kernel_launch(void* const* d_in, const int* in_sizes, int n_in,
                              void* d_out, int out_size, void* d_ws, size_t ws_size,
                              hipStream_t stream) {
    const float* x    = (const float*)d_in[0];
    const int*   ei   = (const int*)d_in[1];
    const float* t1w  = (const float*)d_in[2];
    const float* t1b  = (const float*)d_in[3];
    const float* t2w  = (const float*)d_in[4];
    const float* t2b  = (const float*)d_in[5];
    const float* attl = (const float*)d_in[6];
    const float* attr = (const float*)d_in[7];
    float* out = (float*)d_out;

    const int* src = ei;
    const int* dst = ei + NE;

    char* ws = (char*)d_ws;
    size_t off = 0;
    auto alloc = [&](size_t bytes) { char* p = ws + off; off += (bytes + 255) & ~(size_t)255; return p; };
    float*  hA   = (float*)alloc((size_t)NN * HID * 4); // raw / h0
    float*  hB   = (float*)alloc((size_t)NN * HID * 4);
    float*  hC   = (float*)alloc((size_t)NN * HID * 4);
    ushort* wbf  = (ushort*)alloc((size_t)HID * IN_DIM * 2);
    int*    deg  = (int*)alloc((size_t)NN * 4);
    float*  dinv = (float*)alloc((size_t)NN * 4);
    int*    rowptr = (int*)alloc((size_t)(NN + 1) * 4);
    int*    cursor = (int*)alloc((size_t)NN * 4);
    int*    csr_src = (int*)alloc((size_t)NE * 4);
    int*    localScan = (int*)alloc((size_t)NN * 4);
    int*    blockSums = (int*)alloc((size_t)256 * 4);
    int*    blockOff  = (int*)alloc((size_t)256 * 4);
    float2* AD_A = (float2*)alloc((size_t)NN * 8);
    float*  AR_A = (float*)alloc((size_t)NN * 4);
    float2* AD_B = (float2*)alloc((size_t)NN * 8);
    float*  AR_B = (float*)alloc((size_t)NN * 4);
    (void)ws_size;

    hipMemsetAsync(deg, 0, (size_t)NN * 4, stream);

    dim3 blk(256);
    deg_kernel<<<(NE + 255) / 256, blk, 0, stream>>>(dst, deg);
    scanA_kernel<<<NBLK, blk, 0, stream>>>(deg, localScan, blockSums, dinv);
    scanB_kernel<<<1, blk, 0, stream>>>(blockSums, blockOff);
    scanC_kernel<<<NBLK, blk, 0, stream>>>(localScan, blockOff, rowptr, cursor);
    fill_kernel<<<(NE + 255) / 256, blk, 0, stream>>>(src, dst, cursor, csr_src);

    cvtw_kernel<<<(HID * IN_DIM + 255) / 256, blk, 0, stream>>>(t1w, wbf);
    gemm1_kernel<<<(NN + 63) / 64, blk, 0, stream>>>(x, wbf, t1b, hA);

    att0_kernel<<<(NN + 3) / 4, blk, 0, stream>>>(hA, attl + 0 * HID, attr + 0 * HID, dinv, AD_A, AR_A);

    // L0: hA -> hB, epilogue computes layer-1 scalars into AD_B/AR_B
    agg_kernel<<<(NN + 3) / 4, blk, 0, stream>>>(hA, hA, hB, rowptr, csr_src, dinv,
                                                 AD_A, AR_A, attl + 1 * HID, attr + 1 * HID, AD_B, AR_B);
    // L1: hB -> hC, epilogue computes layer-2 scalars into AD_A/AR_A
    agg_kernel<<<(NN + 3) / 4, blk, 0, stream>>>(hB, hA, hC, rowptr, csr_src, dinv,
                                                 AD_B, AR_B, attl + 2 * HID, attr + 2 * HID, AD_A, AR_A);
    // L2: hC -> hB, no epilogue
    agg_kernel<<<(NN + 3) / 4, blk, 0, stream>>>(hC, hA, hB, rowptr, csr_src, dinv,
                                                 AD_A, AR_A, nullptr, nullptr, nullptr, nullptr);

    head_kernel<<<(NN + 3) / 4, blk, 0, stream>>>(hB, t2w, t2b, out);
}

// Round 7
// 487.638 us; speedup vs baseline: 1.0161x; 1.0161x over previous
//
#include <hip/hip_runtime.h>
#include <hip/hip_bf16.h>
#include <stdint.h>

#define NN 50000
#define NE 600000
#define IN_DIM 512
#define HID 128
#define ODIM 64
#define EPSV 0.1f
#define NBLK ((NN + 255) / 256)  // 196 scan blocks

typedef __attribute__((ext_vector_type(8))) short short8;
typedef __attribute__((ext_vector_type(4))) float f32x4;

__device__ __forceinline__ ushort f2bf(float f) {
    union { float f; uint32_t i; } v; v.f = f;
    uint32_t lsb = (v.i >> 16) & 1u;
    uint32_t r = v.i + 0x7fffu + lsb;
    return (ushort)(r >> 16);
}

// fast tanh: (e^2z - 1) / (e^2z + 1), clamped
__device__ __forceinline__ float fast_tanh(float z) {
    z = fminf(fmaxf(z, -15.f), 15.f);
    float t = __expf(2.f * z);
    return __fdividef(t - 1.f, t + 1.f);
}

// ---- degree count ----
__global__ __launch_bounds__(256) void deg_kernel(const int* __restrict__ dst, int* __restrict__ deg) {
    int e = blockIdx.x * 256 + threadIdx.x;
    if (e < NE) atomicAdd(&deg[dst[e]], 1);
}

// ---- scan phase A ----
__global__ __launch_bounds__(256) void scanA_kernel(const int* __restrict__ deg,
                                                    int* __restrict__ localScan,
                                                    int* __restrict__ blockSums,
                                                    float* __restrict__ dinv) {
    __shared__ int tmp[256];
    int t = threadIdx.x;
    int i = blockIdx.x * 256 + t;
    int v = (i < NN) ? deg[i] : 0;
    tmp[t] = v;
    __syncthreads();
    for (int off = 1; off < 256; off <<= 1) {
        int add = (t >= off) ? tmp[t - off] : 0;
        __syncthreads();
        tmp[t] += add;
        __syncthreads();
    }
    if (i < NN) {
        localScan[i] = tmp[t] - v;
        dinv[i] = (v > 0) ? (1.0f / sqrtf((float)v)) : 0.0f;
    }
    if (t == 255) blockSums[blockIdx.x] = tmp[255];
}

// ---- scan phase B ----
__global__ __launch_bounds__(256) void scanB_kernel(const int* __restrict__ blockSums,
                                                    int* __restrict__ blockOff) {
    __shared__ int tmp[256];
    int t = threadIdx.x;
    int v = (t < NBLK) ? blockSums[t] : 0;
    tmp[t] = v;
    __syncthreads();
    for (int off = 1; off < 256; off <<= 1) {
        int add = (t >= off) ? tmp[t - off] : 0;
        __syncthreads();
        tmp[t] += add;
        __syncthreads();
    }
    blockOff[t] = tmp[t] - v;
}

// ---- scan phase C ----
__global__ __launch_bounds__(256) void scanC_kernel(const int* __restrict__ localScan,
                                                    const int* __restrict__ blockOff,
                                                    int* __restrict__ rowptr,
                                                    int* __restrict__ cursor) {
    int i = blockIdx.x * 256 + threadIdx.x;
    if (i < NN) {
        int v = localScan[i] + blockOff[blockIdx.x];
        rowptr[i] = v;
        cursor[i] = v;
    }
    if (i == 0) rowptr[NN] = NE;
}

// ---- fill CSR ----
__global__ __launch_bounds__(256) void fill_kernel(const int* __restrict__ src, const int* __restrict__ dst,
                                                   int* __restrict__ cursor, int* __restrict__ csr_src) {
    int e = blockIdx.x * 256 + threadIdx.x;
    if (e < NE) {
        int d = dst[e];
        int slot = atomicAdd(&cursor[d], 1);
        csr_src[slot] = src[e];
    }
}

// ---- convert W1 fp32 -> bf16 ----
__global__ __launch_bounds__(256) void cvtw_kernel(const float* __restrict__ w, ushort* __restrict__ wbf) {
    int i = blockIdx.x * 256 + threadIdx.x;
    if (i < HID * IN_DIM) wbf[i] = f2bf(w[i]);
}

// ---- h0 = relu(x @ W1^T + b1): pipelined 64-row tile, LDS bf16 A-staging ----
// K-step order de-phased per block: phase = (blockIdx.x + s_idx) & 7 so that at
// any instant different blocks read different 256B column granules -> all HBM
// channels active (fixes the mod-2048B channel-aliasing ~0.9 TB/s ceiling).
__global__ __launch_bounds__(256) void gemm1_kernel(const float* __restrict__ x,
                                                    const ushort* __restrict__ wbf,
                                                    const float* __restrict__ b,
                                                    float* __restrict__ h) {
    __shared__ ushort a_sm[64 * 72]; // 9 KB
    int t = threadIdx.x;
    int wv = __builtin_amdgcn_readfirstlane(t >> 6);
    int lane = t & 63;
    int m0 = blockIdx.x * 64;

    // staging map: thread t covers rows tr+16i, cols [tc, tc+4)
    int tr = t >> 4;          // 0..15
    int tc = (t & 15) * 4;    // 0..60

    // fragment map
    int rsel = lane & 15;
    int koff = (lane >> 4) * 8;
    int rloc = wv * 16 + rsel;

    int r0 = m0 + tr;        if (r0 >= NN) r0 = NN - 1;
    int r1 = m0 + tr + 16;   if (r1 >= NN) r1 = NN - 1;
    int r2 = m0 + tr + 32;   if (r2 >= NN) r2 = NN - 1;
    int r3 = m0 + tr + 48;   if (r3 >= NN) r3 = NN - 1;

    f32x4 acc[8];
#pragma unroll
    for (int tt = 0; tt < 8; ++tt) acc[tt] = (f32x4){0.f, 0.f, 0.f, 0.f};

    // prologue: load this block's starting phase
    float4 p0, p1, p2, p3;
    {
        int k00 = ((blockIdx.x) & 7) * 64;
        p0 = *(const float4*)(x + (size_t)r0 * IN_DIM + k00 + tc);
        p1 = *(const float4*)(x + (size_t)r1 * IN_DIM + k00 + tc);
        p2 = *(const float4*)(x + (size_t)r2 * IN_DIM + k00 + tc);
        p3 = *(const float4*)(x + (size_t)r3 * IN_DIM + k00 + tc);
    }

    for (int si = 0; si < 8; ++si) {
        // write prefetched regs to LDS as bf16
        {
            uint2 u;
            u.x = (uint32_t)f2bf(p0.x) | ((uint32_t)f2bf(p0.y) << 16);
            u.y = (uint32_t)f2bf(p0.z) | ((uint32_t)f2bf(p0.w) << 16);
            *(uint2*)(&a_sm[(tr) * 72 + tc]) = u;
            u.x = (uint32_t)f2bf(p1.x) | ((uint32_t)f2bf(p1.y) << 16);
            u.y = (uint32_t)f2bf(p1.z) | ((uint32_t)f2bf(p1.w) << 16);
            *(uint2*)(&a_sm[(tr + 16) * 72 + tc]) = u;
            u.x = (uint32_t)f2bf(p2.x) | ((uint32_t)f2bf(p2.y) << 16);
            u.y = (uint32_t)f2bf(p2.z) | ((uint32_t)f2bf(p2.w) << 16);
            *(uint2*)(&a_sm[(tr + 32) * 72 + tc]) = u;
            u.x = (uint32_t)f2bf(p3.x) | ((uint32_t)f2bf(p3.y) << 16);
            u.y = (uint32_t)f2bf(p3.z) | ((uint32_t)f2bf(p3.w) << 16);
            *(uint2*)(&a_sm[(tr + 48) * 72 + tc]) = u;
        }
        __syncthreads();
        // fire next K-step's loads (stay in flight through compute + barrier)
        if (si + 1 < 8) {
            int k0n = ((blockIdx.x + si + 1) & 7) * 64;
            p0 = *(const float4*)(x + (size_t)r0 * IN_DIM + k0n + tc);
            p1 = *(const float4*)(x + (size_t)r1 * IN_DIM + k0n + tc);
            p2 = *(const float4*)(x + (size_t)r2 * IN_DIM + k0n + tc);
            p3 = *(const float4*)(x + (size_t)r3 * IN_DIM + k0n + tc);
        }
        // compute current step from LDS
        int k0 = ((blockIdx.x + si) & 7) * 64;
#pragma unroll
        for (int kk = 0; kk < 64; kk += 32) {
            short8 a = *(const short8*)(&a_sm[rloc * 72 + kk + koff]);
#pragma unroll
            for (int tt = 0; tt < 8; ++tt) {
                short8 bf = *(const short8*)(wbf + (size_t)(tt * 16 + rsel) * IN_DIM + k0 + kk + koff);
                acc[tt] = __builtin_amdgcn_mfma_f32_16x16x32_bf16(a, bf, acc[tt], 0, 0, 0);
            }
        }
        __syncthreads();
    }

    // epilogue: bias + relu, straight from accumulators
    int rbase = (lane >> 4) * 4;
    int col0 = lane & 15;
#pragma unroll
    for (int tt = 0; tt < 8; ++tt) {
        int n = tt * 16 + col0;
        float bias = b[n];
#pragma unroll
        for (int r = 0; r < 4; ++r) {
            int row = m0 + wv * 16 + rbase + r;
            if (row < NN) {
                float v = acc[tt][r] + bias;
                v = v > 0.f ? v : 0.f;
                h[(size_t)row * HID + n] = v;
            }
        }
    }
}

// ---- per-node attention scalars for layer 0 ----
__global__ __launch_bounds__(256) void att0_kernel(const float* __restrict__ h,
                                                   const float* __restrict__ attl,
                                                   const float* __restrict__ attr,
                                                   const float* __restrict__ dinv,
                                                   float2* __restrict__ AD,
                                                   float* __restrict__ AR) {
    int wv = __builtin_amdgcn_readfirstlane(threadIdx.x >> 6);
    int lane = threadIdx.x & 63;
    int d = blockIdx.x * 4 + wv;
    if (d >= NN) return;
    float al0 = attl[2 * lane], al1 = attl[2 * lane + 1];
    float ar0 = attr[2 * lane], ar1 = attr[2 * lane + 1];
    float2 hd = ((const float2*)h)[(size_t)d * 64 + lane];
    float p = hd.x * al0 + hd.y * al1;
    float q = hd.x * ar0 + hd.y * ar1;
#pragma unroll
    for (int off = 32; off; off >>= 1) { p += __shfl_xor(p, off); q += __shfl_xor(q, off); }
    if (lane == 0) {
        float2 v; v.x = p; v.y = dinv[d];
        AD[d] = v;
        AR[d] = q;
    }
}

// ---- FAConv aggregation: wave per dst node ----
__global__ __launch_bounds__(256) void agg_kernel(const float* __restrict__ h,
                                                  const float* __restrict__ raw,
                                                  float* __restrict__ hn,
                                                  const int* __restrict__ rowptr,
                                                  const int* __restrict__ csr_src,
                                                  const float* __restrict__ dinv,
                                                  const float2* __restrict__ AD,
                                                  const float* __restrict__ AR,
                                                  const float* __restrict__ attl_next,
                                                  const float* __restrict__ attr_next,
                                                  float2* __restrict__ ADout,
                                                  float* __restrict__ ARout) {
    int wv = __builtin_amdgcn_readfirstlane(threadIdx.x >> 6);
    int lane = threadIdx.x & 63;
    int d = blockIdx.x * 4 + wv;
    if (d >= NN) return;
    const float2* h2 = (const float2*)h;
    float ar_d = AR[d];
    float dinv_d = dinv[d];
    float2 rawd = ((const float2*)raw)[(size_t)d * 64 + lane];
    float accx = EPSV * rawd.x, accy = EPSV * rawd.y;
    int e = rowptr[d], e1 = rowptr[d + 1];
    for (; e + 4 <= e1; e += 4) {
        int s0 = __builtin_amdgcn_readfirstlane(csr_src[e]);
        int s1 = __builtin_amdgcn_readfirstlane(csr_src[e + 1]);
        int s2 = __builtin_amdgcn_readfirstlane(csr_src[e + 2]);
        int s3 = __builtin_amdgcn_readfirstlane(csr_src[e + 3]);
        float2 ad0 = AD[s0], ad1 = AD[s1], ad2 = AD[s2], ad3 = AD[s3];
        float2 v0 = h2[(size_t)s0 * 64 + lane];
        float2 v1 = h2[(size_t)s1 * 64 + lane];
        float2 v2 = h2[(size_t)s2 * 64 + lane];
        float2 v3 = h2[(size_t)s3 * 64 + lane];
        float w0 = fast_tanh(ad0.x + ar_d) * ad0.y * dinv_d;
        float w1 = fast_tanh(ad1.x + ar_d) * ad1.y * dinv_d;
        float w2 = fast_tanh(ad2.x + ar_d) * ad2.y * dinv_d;
        float w3 = fast_tanh(ad3.x + ar_d) * ad3.y * dinv_d;
        accx += w0 * v0.x + w1 * v1.x + w2 * v2.x + w3 * v3.x;
        accy += w0 * v0.y + w1 * v1.y + w2 * v2.y + w3 * v3.y;
    }
    for (; e < e1; ++e) {
        int s = __builtin_amdgcn_readfirstlane(csr_src[e]);
        float2 ad = AD[s];
        float2 v = h2[(size_t)s * 64 + lane];
        float w = fast_tanh(ad.x + ar_d) * ad.y * dinv_d;
        accx += w * v.x;
        accy += w * v.y;
    }
    float2 o; o.x = accx; o.y = accy;
    ((float2*)hn)[(size_t)d * 64 + lane] = o;
    if (attl_next) {
        float al0 = attl_next[2 * lane], al1 = attl_next[2 * lane + 1];
        float ar0 = attr_next[2 * lane], ar1 = attr_next[2 * lane + 1];
        float p = accx * al0 + accy * al1;
        float q = accx * ar0 + accy * ar1;
#pragma unroll
        for (int off = 32; off; off >>= 1) { p += __shfl_xor(p, off); q += __shfl_xor(q, off); }
        if (lane == 0) {
            float2 v; v.x = p; v.y = dinv_d;
            ADout[d] = v;
            ARout[d] = q;
        }
    }
}

// ---- head: emb = h @ W2^T + b2; out0 = log_softmax(emb); out1 = emb ----
__global__ __launch_bounds__(256) void head_kernel(const float* __restrict__ h,
                                                   const float* __restrict__ w2,
                                                   const float* __restrict__ b2,
                                                   float* __restrict__ out) {
    __shared__ float w2t[HID * 65];
    int t = threadIdx.x;
    for (int i = t; i < HID * ODIM; i += 256) {
        int j = i >> 7, k = i & 127;
        w2t[k * 65 + j] = w2[i];
    }
    __syncthreads();
    int lane = t & 63;
    int wv = __builtin_amdgcn_readfirstlane(t >> 6);
    int d = blockIdx.x * 4 + wv;
    if (d >= NN) return;
    const float* hr = h + (size_t)d * HID;
    float ea = b2[lane], eb = 0.f;
#pragma unroll 8
    for (int k = 0; k < HID; k += 2) {
        ea += hr[k] * w2t[k * 65 + lane];
        eb += hr[k + 1] * w2t[(k + 1) * 65 + lane];
    }
    float e = ea + eb;
    float m = e;
#pragma unroll
    for (int off = 32; off; off >>= 1) m = fmaxf(m, __shfl_xor(m, off));
    float ex = __expf(e - m);
    float s = ex;
#pragma unroll
    for (int off = 32; off; off >>= 1) s += __shfl_xor(s, off);
    float lsm = e - m - __logf(s);
    out[(size_t)d * ODIM + lane] = lsm;
    out[(size_t)NN * ODIM + (size_t)d * ODIM + lane] = e;
}

extern "C" void kernel_launch(void* const* d_in, const int* in_sizes, int n_in,
                              void* d_out, int out_size, void* d_ws, size_t ws_size,
                              hipStream_t stream) {
    const float* x    = (const float*)d_in[0];
    const int*   ei   = (const int*)d_in[1];
    const float* t1w  = (const float*)d_in[2];
    const float* t1b  = (const float*)d_in[3];
    const float* t2w  = (const float*)d_in[4];
    const float* t2b  = (const float*)d_in[5];
    const float* attl = (const float*)d_in[6];
    const float* attr = (const float*)d_in[7];
    float* out = (float*)d_out;

    const int* src = ei;
    const int* dst = ei + NE;

    char* ws = (char*)d_ws;
    size_t off = 0;
    auto alloc = [&](size_t bytes) { char* p = ws + off; off += (bytes + 255) & ~(size_t)255; return p; };
    float*  hA   = (float*)alloc((size_t)NN * HID * 4); // raw / h0
    float*  hB   = (float*)alloc((size_t)NN * HID * 4);
    float*  hC   = (float*)alloc((size_t)NN * HID * 4);
    ushort* wbf  = (ushort*)alloc((size_t)HID * IN_DIM * 2);
    int*    deg  = (int*)alloc((size_t)NN * 4);
    float*  dinv = (float*)alloc((size_t)NN * 4);
    int*    rowptr = (int*)alloc((size_t)(NN + 1) * 4);
    int*    cursor = (int*)alloc((size_t)NN * 4);
    int*    csr_src = (int*)alloc((size_t)NE * 4);
    int*    localScan = (int*)alloc((size_t)NN * 4);
    int*    blockSums = (int*)alloc((size_t)256 * 4);
    int*    blockOff  = (int*)alloc((size_t)256 * 4);
    float2* AD_A = (float2*)alloc((size_t)NN * 8);
    float*  AR_A = (float*)alloc((size_t)NN * 4);
    float2* AD_B = (float2*)alloc((size_t)NN * 8);
    float*  AR_B = (float*)alloc((size_t)NN * 4);
    (void)ws_size;

    hipMemsetAsync(deg, 0, (size_t)NN * 4, stream);

    dim3 blk(256);
    deg_kernel<<<(NE + 255) / 256, blk, 0, stream>>>(dst, deg);
    scanA_kernel<<<NBLK, blk, 0, stream>>>(deg, localScan, blockSums, dinv);
    scanB_kernel<<<1, blk, 0, stream>>>(blockSums, blockOff);
    scanC_kernel<<<NBLK, blk, 0, stream>>>(localScan, blockOff, rowptr, cursor);
    fill_kernel<<<(NE + 255) / 256, blk, 0, stream>>>(src, dst, cursor, csr_src);

    cvtw_kernel<<<(HID * IN_DIM + 255) / 256, blk, 0, stream>>>(t1w, wbf);
    gemm1_kernel<<<(NN + 63) / 64, blk, 0, stream>>>(x, wbf, t1b, hA);

    att0_kernel<<<(NN + 3) / 4, blk, 0, stream>>>(hA, attl + 0 * HID, attr + 0 * HID, dinv, AD_A, AR_A);

    // L0: hA -> hB, epilogue computes layer-1 scalars into AD_B/AR_B
    agg_kernel<<<(NN + 3) / 4, blk, 0, stream>>>(hA, hA, hB, rowptr, csr_src, dinv,
                                                 AD_A, AR_A, attl + 1 * HID, attr + 1 * HID, AD_B, AR_B);
    // L1: hB -> hC, epilogue computes layer-2 scalars into AD_A/AR_A
    agg_kernel<<<(NN + 3) / 4, blk, 0, stream>>>(hB, hA, hC, rowptr, csr_src, dinv,
                                                 AD_B, AR_B, attl + 2 * HID, attr + 2 * HID, AD_A, AR_A);
    // L2: hC -> hB, no epilogue
    agg_kernel<<<(NN + 3) / 4, blk, 0, stream>>>(hC, hA, hB, rowptr, csr_src, dinv,
                                                 AD_A, AR_A, nullptr, nullptr, nullptr, nullptr);

    head_kernel<<<(NN + 3) / 4, blk, 0, stream>>>(hB, t2w, t2b, out);
}